// Round 5
// baseline (4499.103 us; speedup 1.0000x reference)
//
#include <hip/hip_runtime.h>
#include <math.h>

// Problem constants
#define BTOT   4096
#define CIN    3
#define TIN    64
#define SIN    128

// ws layout (float offsets)
#define SEQ_OFF    0                            // [4096][60][124]
#define G_OFF      (SEQ_OFF + 4096*60*124)      // [4096][129]
#define HST_OFF    (G_OFF + 4096*129)           // [4096][144] h state between chunks
#define WHH144_OFF (HST_OFF + 4096*144)         // [387][144] padded Whh
#define MUWP_OFF   (WHH144_OFF + 387*144)       // [129][260]
#define LSWP_OFF   (MUWP_OFF + 129*260)         // [129][260]
#define GIC_OFF    (LSWP_OFF + 129*260)         // [CT][387][4096] gi chunk

// ---------------------------------------------------------------------------
// Prep: pad Whh rows 129->144, fc weights rows 258->260
// ---------------------------------------------------------------------------
__global__ __launch_bounds__(256) void prep_pad(
    const float* __restrict__ Whh, const float* __restrict__ muw,
    const float* __restrict__ lsw, float* __restrict__ ws)
{
    int idx = blockIdx.x * 256 + threadIdx.x;
    const int N1 = 387 * 144;
    const int N2 = 129 * 260;
    if (idx < N1) {
        int n = idx / 144, k = idx - n * 144;
        ws[WHH144_OFF + idx] = (k < 129) ? Whh[n * 129 + k] : 0.f;
    } else if (idx < N1 + N2) {
        int i = idx - N1; int j = i / 260, k = i - j * 260;
        ws[MUWP_OFF + i] = (k < 258) ? muw[j * 258 + k] : 0.f;
    } else if (idx < N1 + 2 * N2) {
        int i = idx - N1 - N2; int j = i / 260, k = i - j * 260;
        ws[LSWP_OFF + i] = (k < 258) ? lsw[j * 258 + k] : 0.f;
    }
}

// ---------------------------------------------------------------------------
// Fused conv1+conv2 (both VALID 3x3, leaky) -> seq[B][60][124]
// ---------------------------------------------------------------------------
__global__ __launch_bounds__(256) void conv_fused(
    const float* __restrict__ x,
    const float* __restrict__ w1, const float* __restrict__ b1,
    const float* __restrict__ w2, const float* __restrict__ b2,
    float* __restrict__ seq)
{
    __shared__ __attribute__((aligned(16))) float xt[3 * 14 * 128];
    __shared__ __attribute__((aligned(16))) float h1t[6 * 12 * 128];
    __shared__ float w1s[162];
    __shared__ float w2s[54];
    __shared__ float b1s[6];
    __shared__ float b2s;

    const int tid  = threadIdx.x;
    const int tile = blockIdx.x;   // 0..5
    const int bb   = blockIdx.y;   // batch
    const int T0   = tile * 10;

    if (tid < 162)                  w1s[tid] = w1[tid];
    if (tid >= 192 && tid < 246)    w2s[tid - 192] = w2[tid - 192];
    if (tid >= 248 && tid < 254)    b1s[tid - 248] = b1[tid - 248];
    if (tid == 255)                 b2s = b2[0];

    const float* xb = x + (size_t)bb * CIN * TIN * SIN;
    for (int i = tid; i < 3 * 14 * 128; i += 256) {
        int c = i / (14 * 128);
        int rem = i - c * (14 * 128);
        int t = rem >> 7;
        int s = rem & 127;
        xt[i] = xb[(c * TIN + T0 + t) * SIN + s];
    }
    __syncthreads();

    for (int i = tid; i < 6 * 12 * 126; i += 256) {
        int o = i / (12 * 126);
        int rem = i - o * (12 * 126);
        int t = rem / 126;
        int s = rem - t * 126;
        float acc = b1s[o];
        #pragma unroll
        for (int c = 0; c < 3; ++c)
            #pragma unroll
            for (int kt = 0; kt < 3; ++kt)
                #pragma unroll
                for (int ks = 0; ks < 3; ++ks)
                    acc += xt[(c * 14 + t + kt) * 128 + (s + ks)] *
                           w1s[(o * 3 + c) * 9 + kt * 3 + ks];
        h1t[(o * 12 + t) * 128 + s] = (acc >= 0.f) ? acc : 0.01f * acc;
    }
    __syncthreads();

    for (int i = tid; i < 10 * 124; i += 256) {
        int t = i / 124;
        int s = i - t * 124;
        float acc = b2s;
        #pragma unroll
        for (int o = 0; o < 6; ++o)
            #pragma unroll
            for (int kt = 0; kt < 3; ++kt)
                #pragma unroll
                for (int ks = 0; ks < 3; ++ks)
                    acc += h1t[(o * 12 + t + kt) * 128 + (s + ks)] *
                           w2s[o * 9 + kt * 3 + ks];
        float v = (acc >= 0.f) ? acc : 0.01f * acc;
        seq[((size_t)bb * 60 + T0 + t) * 124 + s] = v;
    }
}

// ---------------------------------------------------------------------------
// gi GEMM: giT[tt][387][4096] = seq[:, t, :] @ Wih^T  for t in chunk.
// Block: 256 b-rows at fixed t, 512 threads = 8 waves.
// Lane = (khalf, row32). Row half of seq lives in registers (16 float4).
// Weight loads are wave-uniform per khalf (2 cache lines / instruction).
// ---------------------------------------------------------------------------
__global__ __launch_bounds__(512) void gi_gemm(
    const float* __restrict__ seq, const float* __restrict__ Wih,
    float* __restrict__ gic, int t0)
{
    const int tid  = threadIdx.x;
    const int wv   = tid >> 6;        // 0..7
    const int lane = tid & 63;
    const int half = lane >> 5;       // 0: k 0..63, 1: k 64..123
    const int r32  = lane & 31;
    const int tt   = blockIdx.y;
    const int t    = t0 + tt;
    const int bcol = blockIdx.x * 256 + wv * 32 + r32;   // batch index

    // preload my half-row of seq into registers
    const float4* srow = (const float4*)(seq + ((size_t)bcol * 60 + t) * 124) + half * 16;
    float4 xr[16];
    #pragma unroll
    for (int i = 0; i < 15; ++i) xr[i] = srow[i];
    float4 x15 = make_float4(0.f, 0.f, 0.f, 0.f);
    if (!half) x15 = srow[15];

    const size_t gtb = (size_t)tt * 387 * 4096 + bcol;

    // 64 full groups of 6 cols
    for (int jg = 0; jg < 64; ++jg) {
        const int j0 = jg * 6;
        float a0 = 0.f, a1 = 0.f, a2 = 0.f, a3 = 0.f, a4 = 0.f, a5 = 0.f;
        const float* wb = Wih + (size_t)j0 * 124 + half * 64;
        #pragma unroll
        for (int ki = 0; ki < 15; ++ki) {
            float4 x = xr[ki];
            float4 w0 = *(const float4*)(wb + 4 * ki);
            float4 w1v = *(const float4*)(wb + 124 + 4 * ki);
            float4 w2v = *(const float4*)(wb + 248 + 4 * ki);
            float4 w3 = *(const float4*)(wb + 372 + 4 * ki);
            float4 w4 = *(const float4*)(wb + 496 + 4 * ki);
            float4 w5 = *(const float4*)(wb + 620 + 4 * ki);
            a0 += x.x*w0.x + x.y*w0.y + x.z*w0.z + x.w*w0.w;
            a1 += x.x*w1v.x + x.y*w1v.y + x.z*w1v.z + x.w*w1v.w;
            a2 += x.x*w2v.x + x.y*w2v.y + x.z*w2v.z + x.w*w2v.w;
            a3 += x.x*w3.x + x.y*w3.y + x.z*w3.z + x.w*w3.w;
            a4 += x.x*w4.x + x.y*w4.y + x.z*w4.z + x.w*w4.w;
            a5 += x.x*w5.x + x.y*w5.y + x.z*w5.z + x.w*w5.w;
        }
        if (!half) {
            float4 x = x15;
            float4 w0 = *(const float4*)(wb + 60);
            float4 w1v = *(const float4*)(wb + 184);
            float4 w2v = *(const float4*)(wb + 308);
            float4 w3 = *(const float4*)(wb + 432);
            float4 w4 = *(const float4*)(wb + 556);
            float4 w5 = *(const float4*)(wb + 680);
            a0 += x.x*w0.x + x.y*w0.y + x.z*w0.z + x.w*w0.w;
            a1 += x.x*w1v.x + x.y*w1v.y + x.z*w1v.z + x.w*w1v.w;
            a2 += x.x*w2v.x + x.y*w2v.y + x.z*w2v.z + x.w*w2v.w;
            a3 += x.x*w3.x + x.y*w3.y + x.z*w3.z + x.w*w3.w;
            a4 += x.x*w4.x + x.y*w4.y + x.z*w4.z + x.w*w4.w;
            a5 += x.x*w5.x + x.y*w5.y + x.z*w5.z + x.w*w5.w;
        }
        // combine k-halves
        a0 += __shfl_xor(a0, 32, 64);
        a1 += __shfl_xor(a1, 32, 64);
        a2 += __shfl_xor(a2, 32, 64);
        a3 += __shfl_xor(a3, 32, 64);
        a4 += __shfl_xor(a4, 32, 64);
        a5 += __shfl_xor(a5, 32, 64);
        size_t gb = gtb + (size_t)j0 * 4096;
        if (!half) {
            gic[gb]          = a0;
            gic[gb + 4096]   = a1;
            gic[gb + 8192]   = a2;
        } else {
            gic[gb + 12288]  = a3;
            gic[gb + 16384]  = a4;
            gic[gb + 20480]  = a5;
        }
    }
    // tail: cols 384..386
    {
        float a0 = 0.f, a1 = 0.f, a2 = 0.f;
        const float* wb = Wih + (size_t)384 * 124 + half * 64;
        #pragma unroll
        for (int ki = 0; ki < 15; ++ki) {
            float4 x = xr[ki];
            float4 w0 = *(const float4*)(wb + 4 * ki);
            float4 w1v = *(const float4*)(wb + 124 + 4 * ki);
            float4 w2v = *(const float4*)(wb + 248 + 4 * ki);
            a0 += x.x*w0.x + x.y*w0.y + x.z*w0.z + x.w*w0.w;
            a1 += x.x*w1v.x + x.y*w1v.y + x.z*w1v.z + x.w*w1v.w;
            a2 += x.x*w2v.x + x.y*w2v.y + x.z*w2v.z + x.w*w2v.w;
        }
        if (!half) {
            float4 x = x15;
            float4 w0 = *(const float4*)(wb + 60);
            float4 w1v = *(const float4*)(wb + 184);
            float4 w2v = *(const float4*)(wb + 308);
            a0 += x.x*w0.x + x.y*w0.y + x.z*w0.z + x.w*w0.w;
            a1 += x.x*w1v.x + x.y*w1v.y + x.z*w1v.z + x.w*w1v.w;
            a2 += x.x*w2v.x + x.y*w2v.y + x.z*w2v.z + x.w*w2v.w;
        }
        a0 += __shfl_xor(a0, 32, 64);
        a1 += __shfl_xor(a1, 32, 64);
        a2 += __shfl_xor(a2, 32, 64);
        size_t gb = gtb + (size_t)384 * 4096;
        if (!half) {
            gic[gb]        = a0;
            gic[gb + 4096] = a1;
        } else {
            gic[gb + 8192] = a2;
        }
    }
}

// ---------------------------------------------------------------------------
// GRU recurrence (gh only): 256 blocks x 1024 threads, 16 rows/block.
// Lane = (kq, row): h quarter (36 floats) in registers; weight loads
// uniform per kq (4 lines/instr, immediate offsets); shfl_xor reduce.
// gi read from global (precomputed, coalesced).
// ---------------------------------------------------------------------------
__global__ __launch_bounds__(1024) void gru_gh(
    const float* __restrict__ gic, const float* __restrict__ whh,  // [387][144]
    const float* __restrict__ bih, const float* __restrict__ bhh,
    float* __restrict__ hstate, float* __restrict__ g_out,
    int t0, int nt)
{
    __shared__ __attribute__((aligned(16))) float hs2[16 * 144];
    __shared__ float GHb[16 * 388];
    __shared__ float bihS[387];
    __shared__ float bhhS[387];

    const int tid  = threadIdx.x;
    const int wv   = tid >> 6;        // 0..15
    const int lane = tid & 63;
    const int kq   = lane >> 4;       // k quarter 0..3 (36 floats each)
    const int row  = lane & 15;
    const int b0   = blockIdx.x * 16;

    if (tid < 387) { bihS[tid] = bih[tid]; bhhS[tid] = bhh[tid]; }
    if (t0 == 0) {
        for (int e = tid; e < 16 * 144; e += 1024) hs2[e] = 0.f;
    } else {
        for (int e = tid; e < 16 * 144; e += 1024) hs2[e] = hstate[(size_t)b0 * 144 + e];
    }
    __syncthreads();

    for (int tt = 0; tt < nt; ++tt) {
        // load my h quarter into registers
        float4 hreg[9];
        {
            const float4* hq = (const float4*)(hs2 + row * 144 + kq * 36);
            #pragma unroll
            for (int i = 0; i < 9; ++i) hreg[i] = hq[i];
        }

        // phase1: gh = h @ Whh^T ; wave wv handles jg = wv, wv+16, ... (4 each)
        for (int jg = wv; jg < 64; jg += 16) {
            const int j0 = jg * 6;
            float a0 = 0.f, a1 = 0.f, a2 = 0.f, a3 = 0.f, a4 = 0.f, a5 = 0.f;
            const float* wb = whh + (size_t)j0 * 144 + kq * 36;
            #pragma unroll
            for (int ki = 0; ki < 9; ++ki) {
                float4 x = hreg[ki];
                float4 w0 = *(const float4*)(wb + 4 * ki);
                float4 w1v = *(const float4*)(wb + 144 + 4 * ki);
                float4 w2v = *(const float4*)(wb + 288 + 4 * ki);
                float4 w3 = *(const float4*)(wb + 432 + 4 * ki);
                float4 w4 = *(const float4*)(wb + 576 + 4 * ki);
                float4 w5 = *(const float4*)(wb + 720 + 4 * ki);
                a0 += x.x*w0.x + x.y*w0.y + x.z*w0.z + x.w*w0.w;
                a1 += x.x*w1v.x + x.y*w1v.y + x.z*w1v.z + x.w*w1v.w;
                a2 += x.x*w2v.x + x.y*w2v.y + x.z*w2v.z + x.w*w2v.w;
                a3 += x.x*w3.x + x.y*w3.y + x.z*w3.z + x.w*w3.w;
                a4 += x.x*w4.x + x.y*w4.y + x.z*w4.z + x.w*w4.w;
                a5 += x.x*w5.x + x.y*w5.y + x.z*w5.z + x.w*w5.w;
            }
            a0 += __shfl_xor(a0, 16, 64); a0 += __shfl_xor(a0, 32, 64);
            a1 += __shfl_xor(a1, 16, 64); a1 += __shfl_xor(a1, 32, 64);
            a2 += __shfl_xor(a2, 16, 64); a2 += __shfl_xor(a2, 32, 64);
            a3 += __shfl_xor(a3, 16, 64); a3 += __shfl_xor(a3, 32, 64);
            a4 += __shfl_xor(a4, 16, 64); a4 += __shfl_xor(a4, 32, 64);
            a5 += __shfl_xor(a5, 16, 64); a5 += __shfl_xor(a5, 32, 64);
            // all lanes hold full sums; spread writes across kq
            float v1 = (kq == 0) ? a0 : (kq == 1) ? a1 : (kq == 2) ? a2 : a3;
            GHb[row * 388 + j0 + kq] = v1;
            if (kq < 2) {
                float v2 = (kq == 0) ? a4 : a5;
                GHb[row * 388 + j0 + 4 + kq] = v2;
            }
        }
        if (wv == 0) {  // tail cols 384..386
            float a0 = 0.f, a1 = 0.f, a2 = 0.f;
            const float* wb = whh + (size_t)384 * 144 + kq * 36;
            #pragma unroll
            for (int ki = 0; ki < 9; ++ki) {
                float4 x = hreg[ki];
                float4 w0 = *(const float4*)(wb + 4 * ki);
                float4 w1v = *(const float4*)(wb + 144 + 4 * ki);
                float4 w2v = *(const float4*)(wb + 288 + 4 * ki);
                a0 += x.x*w0.x + x.y*w0.y + x.z*w0.z + x.w*w0.w;
                a1 += x.x*w1v.x + x.y*w1v.y + x.z*w1v.z + x.w*w1v.w;
                a2 += x.x*w2v.x + x.y*w2v.y + x.z*w2v.z + x.w*w2v.w;
            }
            a0 += __shfl_xor(a0, 16, 64); a0 += __shfl_xor(a0, 32, 64);
            a1 += __shfl_xor(a1, 16, 64); a1 += __shfl_xor(a1, 32, 64);
            a2 += __shfl_xor(a2, 16, 64); a2 += __shfl_xor(a2, 32, 64);
            if (kq < 3) {
                float v = (kq == 0) ? a0 : (kq == 1) ? a1 : a2;
                GHb[row * 388 + 384 + kq] = v;
            }
        }
        __syncthreads();

        // phase2: gates + h update
        const float* gib = gic + (size_t)tt * 387 * 4096 + b0;
        #pragma unroll
        for (int p = 0; p < 3; ++p) {
            int e = tid + p * 1024;
            if (e < 2064) {
                int r = e & 15;
                int j = e >> 4;
                float gr = gib[(size_t)j * 4096 + r];
                float gz = gib[(size_t)(129 + j) * 4096 + r];
                float gn = gib[(size_t)(258 + j) * 4096 + r];
                float pr  = gr + GHb[r * 388 + j]       + bihS[j]       + bhhS[j];
                float pz  = gz + GHb[r * 388 + 129 + j] + bihS[129 + j] + bhhS[129 + j];
                float gin = gn + bihS[258 + j];
                float ghn = GHb[r * 388 + 258 + j] + bhhS[258 + j];
                float rr_ = 1.f / (1.f + __expf(-pr));
                float zz  = 1.f / (1.f + __expf(-pz));
                float nn  = tanhf(gin + rr_ * ghn);
                float ho  = hs2[r * 144 + j];
                hs2[r * 144 + j] = (1.f - zz) * nn + zz * ho;
            }
        }
        __syncthreads();
    }

    // persist h
    for (int e = tid; e < 16 * 144; e += 1024) hstate[(size_t)b0 * 144 + e] = hs2[e];
    if (t0 + nt >= 60) {
        #pragma unroll
        for (int p = 0; p < 3; ++p) {
            int e = tid + p * 1024;
            if (e < 2064) {
                int r = e & 15;
                int j = e >> 4;
                float v = hs2[r * 144 + j];
                g_out[(size_t)(b0 + r) * 129 + j] = (v >= 0.f) ? v : 0.01f * v;
            }
        }
    }
}

// ---------------------------------------------------------------------------
// Head: feat=[g,w] (258) -> mu, log_std -> sample, tanh, log_pi, normalize.
// ---------------------------------------------------------------------------
__global__ __launch_bounds__(256) void head_kernel(
    const float* __restrict__ gbuf, const float* __restrict__ wvec,
    const float* __restrict__ eps,
    const float* __restrict__ muwp, const float* __restrict__ lswp,
    const float* __restrict__ mub,  const float* __restrict__ lsb,
    float* __restrict__ out)
{
    __shared__ __attribute__((aligned(16))) float feat[16 * 260];
    __shared__ float PA[16 * 130];
    __shared__ float TERM[16 * 130];
    __shared__ float ROWSUM[16];
    __shared__ float ROWLOG[16];

    const int tid = threadIdx.x;
    const int b0  = blockIdx.x * 16;

    for (int i = tid; i < 16 * 260; i += 256) {
        int r = i / 260;
        int k = i - r * 260;
        float v = 0.f;
        if (k < 129)       v = gbuf[(size_t)(b0 + r) * 129 + k];
        else if (k < 258)  v = wvec[(size_t)(b0 + r) * 129 + (k - 129)];
        feat[i] = v;
    }
    __syncthreads();

    for (int idx = tid; idx < 16 * 129; idx += 256) {
        int r = idx & 15;
        int j = idx >> 4;
        const float4* fv = (const float4*)(feat + r * 260);
        const float4* mw = (const float4*)(muwp + (size_t)j * 260);
        const float4* lw = (const float4*)(lswp + (size_t)j * 260);
        float am = 0.f, al = 0.f;
        for (int k = 0; k < 65; ++k) {
            float4 f = fv[k];
            float4 m = mw[k];
            float4 l = lw[k];
            am += f.x * m.x + f.y * m.y + f.z * m.z + f.w * m.w;
            al += f.x * l.x + f.y * l.y + f.z * l.z + f.w * l.w;
        }
        float mu = am + mub[j];
        float ls = fminf(fmaxf(al + lsb[j], -20.f), 2.f);
        float sd = expf(ls);
        float e  = eps[(size_t)(b0 + r) * 129 + j];
        float xv = mu + sd * e;
        float pa = tanhf(xv);
        float tt = (xv - mu) / sd;
        float term = -0.5f * tt * tt - ls - 0.91893853320467274f
                     - logf(1.f - pa * pa + 1e-6f);
        PA[r * 130 + j]   = pa;
        TERM[r * 130 + j] = term;
    }
    __syncthreads();

    {
        int r = tid >> 4;
        int i = tid & 15;
        float sp = 0.f, st = 0.f;
        for (int j = i; j < 129; j += 16) {
            sp += PA[r * 130 + j];
            st += TERM[r * 130 + j];
        }
        for (int off = 8; off > 0; off >>= 1) {
            sp += __shfl_down(sp, off, 16);
            st += __shfl_down(st, off, 16);
        }
        if (i == 0) { ROWSUM[r] = sp + 129.f; ROWLOG[r] = st; }
    }
    __syncthreads();

    for (int idx = tid; idx < 16 * 129; idx += 256) {
        int r = idx & 15;
        int j = idx >> 4;
        out[(size_t)(b0 + r) * 129 + j] = (PA[r * 130 + j] + 1.f) / ROWSUM[r];
    }
    if (tid < 16)
        out[(size_t)4096 * 129 + b0 + tid] = ROWLOG[tid];
}

// ---------------------------------------------------------------------------
extern "C" void kernel_launch(void* const* d_in, const int* in_sizes, int n_in,
                              void* d_out, int out_size, void* d_ws, size_t ws_size,
                              hipStream_t stream)
{
    const float* x   = (const float*)d_in[0];
    const float* wv  = (const float*)d_in[1];
    const float* eps = (const float*)d_in[2];
    const float* c1w = (const float*)d_in[3];
    const float* c1b = (const float*)d_in[4];
    const float* c2w = (const float*)d_in[5];
    const float* c2b = (const float*)d_in[6];
    const float* Wih = (const float*)d_in[7];
    const float* Whh = (const float*)d_in[8];
    const float* bih = (const float*)d_in[9];
    const float* bhh = (const float*)d_in[10];
    const float* muw = (const float*)d_in[11];
    const float* mub = (const float*)d_in[12];
    const float* lsw = (const float*)d_in[13];
    const float* lsb = (const float*)d_in[14];

    float* ws     = (float*)d_ws;
    float* seq    = ws + SEQ_OFF;
    float* g      = ws + G_OFF;
    float* hstate = ws + HST_OFF;
    float* whh144 = ws + WHH144_OFF;
    float* muwp   = ws + MUWP_OFF;
    float* lswp   = ws + LSWP_OFF;
    float* gic    = ws + GIC_OFF;
    float* outp   = (float*)d_out;

    // chunk size over t, limited by workspace (deterministic given ws_size)
    const long per_t = 387L * 4096;
    long avail = (long)(ws_size / 4) - (long)GIC_OFF;
    int CT = 60;
    if (avail < 60 * per_t) {
        CT = (int)(avail / per_t);
        if (CT < 1) CT = 1;
        if (CT > 60) CT = 60;
    }

    const int prep_elems = 387 * 144 + 2 * (129 * 260);
    prep_pad<<<(prep_elems + 255) / 256, 256, 0, stream>>>(Whh, muw, lsw, ws);
    conv_fused<<<dim3(6, BTOT), 256, 0, stream>>>(x, c1w, c1b, c2w, c2b, seq);

    for (int t0 = 0; t0 < 60; t0 += CT) {
        int nt = 60 - t0; if (nt > CT) nt = CT;
        gi_gemm<<<dim3(16, nt), 512, 0, stream>>>(seq, Wih, gic, t0);
        gru_gh<<<256, 1024, 0, stream>>>(gic, whh144, bih, bhh, hstate, g, t0, nt);
    }
    head_kernel<<<BTOT / 16, 256, 0, stream>>>(g, wv, eps, muwp, lswp, mub, lsb, outp);
}